// Round 2
// baseline (231.330 us; speedup 1.0000x reference)
//
#include <hip/hip_runtime.h>
#include <math.h>

#define B_N   2048
#define NM    128
#define M_N   256
#define LNUM  10
#define EPS_Sf 1e-6f

typedef _Float16 half8 __attribute__((ext_vector_type(8)));
typedef float floatx4 __attribute__((ext_vector_type(4)));

__device__ __forceinline__ float frcp(float x) { return __builtin_amdgcn_rcpf(x); }

// ---------------- workspace layout (float offsets) ----------------
static constexpr size_t o_AA  = 0;                       // 2 f16 planes, frag order
static constexpr size_t o_D   = o_AA  + 131072;          // 256
static constexpr size_t o_yn  = o_D   + 256;             // 2048
static constexpr size_t o_AY  = o_yn  + 2048;            // float2[B*M]
static constexpr size_t o_AYt = o_AY  + 1048576;         // [2][256][2048]
static constexpr size_t o_w2t = o_AYt + 1048576;         // Wa f16 [oc64][kk9][ic32]
static constexpr size_t o_z1  = o_w2t + 18432;           // (unused since conv fusion)
static constexpr size_t o_fp  = o_z1  + 16777216;        // [16][64][2048] fp32 partials
static constexpr size_t o_f   = o_fp  + 2097152;         // [64][2048]
static constexpr size_t o_c   = o_f   + 131072;          // [2048][9]
static constexpr size_t o_dd  = o_c   + 18432;           // [2048][9]
static constexpr size_t o_T   = o_dd  + 18432;           // [2048][10]
static constexpr size_t o_Ua  = o_T   + 20480;           // 524288
static constexpr size_t o_gm  = o_Ua  + 524288;          // 1

// ---------------- K_pre: fused {gm=0, AA->f16 frag, w2 transpose, AY} ----------------
// blocks [0,256) : k_aa rows ; [256,328) : w2t ; [328,584) : k_ay groups
__global__ void k_pre(const float* __restrict__ Ar, const float* __restrict__ Ai,
                      const float* __restrict__ Yr, const float* __restrict__ Yi,
                      const float* __restrict__ w2, float* __restrict__ ws) {
    __shared__ float sb[2048];
    int blk = blockIdx.x;
    int tid = threadIdx.x;
    if (blk < 256) {
        float* cr = sb; float* ci = sb + NM;
        int i = blk, j = tid;
        if (j < NM) { cr[j] = Ar[j * M_N + i]; ci[j] = Ai[j * M_N + i]; }
        __syncthreads();
        float sr = 0.f, si = 0.f;
        for (int n = 0; n < NM; ++n) {
            float ar = Ar[n * M_N + j], ai = Ai[n * M_N + j];
            sr += cr[n] * ar + ci[n] * ai;
            si += cr[n] * ai - ci[n] * ar;
        }
        _Float16* A16 = (_Float16*)(ws + o_AA);
        size_t off = ((size_t)((i >> 4) * 8 + (j >> 5)) * 64
                      + (size_t)(((j >> 3) & 3) * 16 + (i & 15))) * 8 + (j & 7);
        A16[off]         = (_Float16)sr;
        A16[65536 + off] = (_Float16)si;
        if (j == i) ws[o_D + i] = sr;
        if (i == 0 && j == 0) *(unsigned int*)(ws + o_gm) = 0u;
    } else if (blk < 328) {
        int i = (blk - 256) * 256 + tid;
        if (i < 64 * 32 * 9) {
            int oc = i / 288, r = i % 288;
            int ic = r / 9, kk = r % 9;
            _Float16* Wa = (_Float16*)(ws + o_w2t);
            Wa[((size_t)oc * 9 + kk) * 32 + ic] = (_Float16)w2[i];
        }
    } else {
        float2* Ys = (float2*)sb;
        int bb0 = (blk - 328) * 8;
        for (int i = tid; i < 8 * NM; i += 256) {
            int g = i >> 7, n = i & 127;
            Ys[g * NM + n] = make_float2(Yr[(size_t)(bb0 + g) * NM + n],
                                         Yi[(size_t)(bb0 + g) * NM + n]);
        }
        __syncthreads();
        if (tid < 8) {
            float s = 0.f;
            for (int n = 0; n < NM; ++n) { float2 y = Ys[tid * NM + n]; s += y.x * y.x + y.y * y.y; }
            ws[o_yn + bb0 + tid] = s;
        }
        int m = tid;
        float accr[8], acci[8];
#pragma unroll
        for (int g = 0; g < 8; ++g) { accr[g] = 0.f; acci[g] = 0.f; }
        for (int n = 0; n < NM; ++n) {
            float ar = Ar[n * M_N + m], ai = Ai[n * M_N + m];
#pragma unroll
            for (int g = 0; g < 8; ++g) {
                float2 y = Ys[g * NM + n];
                accr[g] += ar * y.x + ai * y.y;
                acci[g] += ar * y.y - ai * y.x;
            }
        }
        float2* AY = (float2*)(ws + o_AY);
#pragma unroll
        for (int g = 0; g < 8; ++g) {
            AY[(size_t)(bb0 + g) * M_N + m] = make_float2(accr[g], acci[g]);
            ws[o_AYt + (size_t)m * B_N + (bb0 + g)] = accr[g];
            ws[o_AYt + 524288 + (size_t)m * B_N + (bb0 + g)] = acci[g];
        }
    }
}

// ---------------- K2: fused conv1+conv2, both as MFMA implicit GEMM ----------------
// conv1: K=18 (2ch x 3x3) padded to 32; weights = A-frag in regs (kills the 576
// wave-uniform LDS weight reads/point of the old k_conv1); output z-tile (18x18 halo,
// 32ch padded to 40 halves for uniform LDS bank-groups) lives only in LDS.
// conv2: identical fragment math to the verified k_conv2m, B-frags from LDS z-tile.
// k-order for conv1 GEMM: k = 2*(dm*3+db) + c  ->  w1 idx = (k&1)*9 + (k>>1).
#define MFMA16(A,Bv,C) C = __builtin_amdgcn_mfma_f32_16x16x32_f16(A, Bv, C, 0, 0, 0)
__global__ void __launch_bounds__(256)
k_conv12(const float* __restrict__ w1, const float* __restrict__ b1,
         const float* __restrict__ b2, float* __restrict__ ws) {
    __shared__ __align__(16) _Float16 zt[18 * 18 * 40];   // 25920 B
    int tid = threadIdx.x;
    int lane = tid & 63, w = tid >> 6;          // 4 waves
    int col = lane & 15, quad = lane >> 4;
    int bt = blockIdx.x & 127, g = blockIdx.x >> 7;
    int b0 = bt * 16, m0 = g * 16;

    // ---- conv1 A-frags (weights) + bias, built once per lane ----
    half8 Aw[2];
#pragma unroll
    for (int t = 0; t < 2; ++t)
#pragma unroll
        for (int j = 0; j < 8; ++j) {
            int k = quad * 8 + j;
            int oc = t * 16 + col;
            Aw[t][j] = (k < 18) ? (_Float16)w1[oc * 18 + (k & 1) * 9 + (k >> 1)]
                                : (_Float16)0.f;
        }
    float b1a[4], b1b[4];
#pragma unroll
    for (int r = 0; r < 4; ++r) { b1a[r] = b1[quad * 4 + r]; b1b[r] = b1[16 + quad * 4 + r]; }

    // per-j decode of k = quad*8+j -> (c, dm, db); invalid k forces row-bound fail
    int dmj[8], dbj[8], offc[8];
#pragma unroll
    for (int j = 0; j < 8; ++j) {
        int k = quad * 8 + j;
        int e = k >> 1;
        int dm = (e * 11) >> 5;          // e/3 for e in [0,15]
        int db = e - dm * 3;
        if (k >= 18) dm = 1 << 20;       // kill via bounds check
        dmj[j] = dm; dbj[j] = db;
        offc[j] = (k & 1) * 524288;
    }

    // ---- conv1: 21 groups of 16 points (324 halo points), groups strided by wave ----
    const float* xr = ws + o_AYt;
    for (int grp = w; grp < 21; grp += 4) {
        int p = grp * 16 + col;
        int mz = (p * 57) >> 10;         // p/18 for p in [0,335]
        int bz = p - mz * 18;
        int m_pt = m0 - 2 + mz, b_pt = b0 - 2 + bz;
        bool pok = (p < 324);
        half8 xb;
#pragma unroll
        for (int j = 0; j < 8; ++j) {
            int row = m_pt + dmj[j], bc = b_pt + dbj[j];
            bool ok = pok && ((unsigned)row < (unsigned)M_N) && ((unsigned)bc < (unsigned)B_N);
            float v = ok ? xr[(size_t)offc[j] + (size_t)row * B_N + bc] : 0.f;
            xb[j] = (_Float16)v;
        }
        floatx4 z0 = (floatx4){0.f, 0.f, 0.f, 0.f};
        floatx4 z1v = (floatx4){0.f, 0.f, 0.f, 0.f};
        MFMA16(Aw[0], xb, z0);
        MFMA16(Aw[1], xb, z1v);
        bool zok = ((unsigned)(m0 - 1 + mz) < (unsigned)M_N) &&
                   ((unsigned)(b0 - 1 + bz) < (unsigned)B_N);
        unsigned long long u0 = 0ull, u1 = 0ull;
        if (zok) {
            union { _Float16 h[4]; unsigned long long u; } a;
#pragma unroll
            for (int r = 0; r < 4; ++r) a.h[r] = (_Float16)fmaxf(z0[r] + b1a[r], 0.f);
            u0 = a.u;
#pragma unroll
            for (int r = 0; r < 4; ++r) a.h[r] = (_Float16)fmaxf(z1v[r] + b1b[r], 0.f);
            u1 = a.u;
        }
        if (pok) {
            _Float16* d = zt + (size_t)(mz * 18 + bz) * 40 + quad * 4;
            *(unsigned long long*)(d)      = u0;   // ch quad*4..+3
            *(unsigned long long*)(d + 16) = u1;   // ch 16+quad*4..+3
        }
    }

    // ---- conv2 A-frags + bias (global, issued before the barrier) ----
    const _Float16* Wa = (const _Float16*)(ws + o_w2t);
    int oc0w = w * 16;
    half8 Af[9];
#pragma unroll
    for (int kk = 0; kk < 9; ++kk)
        Af[kk] = *(const half8*)(Wa + ((size_t)(oc0w + col) * 9 + kk) * 32 + quad * 8);
    float bias2[4];
#pragma unroll
    for (int r = 0; r < 4; ++r) bias2[r] = b2[oc0w + quad * 4 + r];

    __syncthreads();

    // ---- conv2 implicit GEMM from LDS z-tile; row stride 720 halves ----
    const _Float16* zb = zt + (size_t)col * 40 + (size_t)quad * 8;
    half8 Bf[3][3];
#pragma unroll
    for (int ph = 0; ph < 3; ++ph)
#pragma unroll
        for (int db = 0; db < 3; ++db)
            Bf[ph][db] = *(const half8*)(zb + (size_t)ph * 720 + (size_t)db * 40);

    floatx4 facc = (floatx4){0.f, 0.f, 0.f, 0.f};
#pragma unroll
    for (int mm = 0; mm < 16; ++mm) {
        floatx4 a0 = (floatx4){0.f, 0.f, 0.f, 0.f};
#pragma unroll
        for (int dm = 0; dm < 3; ++dm) {
            int ph = (mm + dm) % 3;
#pragma unroll
            for (int db = 0; db < 3; ++db)
                MFMA16(Af[dm * 3 + db], Bf[ph][db], a0);
        }
#pragma unroll
        for (int r = 0; r < 4; ++r) facc[r] += fmaxf(a0[r] + bias2[r], 0.f);
        if (mm < 15) {
            int ph = mm % 3;
#pragma unroll
            for (int db = 0; db < 3; ++db)
                Bf[ph][db] = *(const half8*)(zb + (size_t)(mm + 3) * 720 + (size_t)db * 40);
        }
    }
    float* fp = ws + o_fp + (size_t)g * 131072;
#pragma unroll
    for (int r = 0; r < 4; ++r)
        fp[(size_t)(oc0w + quad * 4 + r) * B_N + b0 + col] = facc[r];
}

// ---------------- K3b: reduce 16 partials -> f = mean over M ----------------
__global__ void k_fred(float* __restrict__ ws) {
    size_t i = (size_t)blockIdx.x * 256 + threadIdx.x;
    float s = 0.f;
    for (int p = 0; p < 16; ++p) s += ws[o_fp + (size_t)p * 131072 + i];
    ws[o_f + i] = s * (1.f / 256.f);
}

// ---------------- K4: c,d,T 1-D convs; one l per block-row (grid 224) ----------------
__global__ void k_cdt(const float* __restrict__ hcw, const float* __restrict__ hcb,
                      const float* __restrict__ hdw, const float* __restrict__ hdb,
                      const float* __restrict__ hTw, const float* __restrict__ hTb,
                      float* __restrict__ ws, float* __restrict__ out) {
    int l = blockIdx.x >> 3;
    int b = (blockIdx.x & 7) * 256 + threadIdx.x;
    const float* f = ws + o_f;
    const float* w; float bi; int li, kind;
    if (l < 9)       { kind = 0; li = l;      w = hcw + (size_t)li * 192; bi = hcb[li]; }
    else if (l < 18) { kind = 1; li = l - 9;  w = hdw + (size_t)li * 192; bi = hdb[li]; }
    else             { kind = 2; li = l - 18; w = hTw + (size_t)li * 192; bi = hTb[li]; }
    __shared__ float wsm[192];
    for (int i = threadIdx.x; i < 192; i += 256) wsm[i] = w[i];
    __syncthreads();
    float acc = bi;
    bool okL = (b > 0), okR = (b < B_N - 1);
    for (int ic = 0; ic < 64; ++ic) {
        const float* fr = f + (size_t)ic * B_N + b;
        float fm1 = okL ? fr[-1] : 0.f;
        float f0  = fr[0];
        float fp1 = okR ? fr[1] : 0.f;
        acc += fm1 * wsm[ic * 3] + f0 * wsm[ic * 3 + 1] + fp1 * wsm[ic * 3 + 2];
    }
    float v = fmaxf(fabsf(acc), 1e-6f);
    if (kind != 1) v = fminf(v, 100.f);
    if (kind == 0)      { ws[o_c  + (size_t)b * 9  + li] = v; if (b == B_N - 1) out[524288 + li] = v; }
    else if (kind == 1) { ws[o_dd + (size_t)b * 9  + li] = v; if (b == B_N - 1) out[524297 + li] = v; }
    else                { ws[o_T  + (size_t)b * 10 + li] = v; if (b == B_N - 1) out[524306 + li] = v; }
}

// ---------------- K5: 10-layer iteration; 8 waves x 32 rows, zero global traffic inside loop ----
__global__ void __launch_bounds__(512, 2)
k_iter(const float* __restrict__ a0p, const float* __restrict__ b0p, float* __restrict__ ws) {
    __shared__ __align__(16) _Float16 Ubf[2][8][64][8];   // 16 KB
    __shared__ __align__(16) float redv[16][28];          // [col][8 waves * 3 + 4 pad]
    __shared__ float redm[8];
    int tid = threadIdx.x;
    int lane = tid & 63, w = tid >> 6;        // w in 0..7
    int col = lane & 15, quad = lane >> 4;
    int b = blockIdx.x * 16 + col;

    for (int i = tid; i < 16 * 28; i += 512) ((float*)redv)[i] = 0.f;

    const float2* AY = (const float2*)(ws + o_AY);
    const _Float16* Af = (const _Float16*)(ws + o_AA);
    float a0 = a0p[0], b0v = b0p[0];
    float atot = a0 + (float)NM;
    float yn = ws[o_yn + b];
    float eps = a0 / b0v;

    half8 Ar8[2][8], Ai8[2][8];
#pragma unroll
    for (int t = 0; t < 2; ++t)
#pragma unroll
        for (int ks = 0; ks < 8; ++ks) {
            const _Float16* ab = Af + (((size_t)(w * 2 + t) * 8 + ks) * 64 + lane) * 8;
            Ar8[t][ks] = *(const half8*)(ab);
            Ai8[t][ks] = *(const half8*)(ab + 65536);
        }

    float Dv[8], ayr[8], ayi[8], lam[8], Ur[8], Ui[8];
    float c0h = ws[o_c + (size_t)b * 9];
    float d0h = ws[o_dd + (size_t)b * 9];
    float T0 = ws[o_T + (size_t)b * 10];
    float lam0 = c0h * frcp(d0h);
#pragma unroll
    for (int ri = 0; ri < 8; ++ri) {
        int m = w * 32 + (ri >> 2) * 16 + quad * 4 + (ri & 3);
        Dv[ri] = ws[o_D + m];
        float2 a = AY[(size_t)b * M_N + m];
        ayr[ri] = a.x; ayi[ri] = a.y;
        lam[ri] = lam0;
    }
    {
        float iv = eps * frcp(fmaf(eps, T0, lam0 + EPS_Sf));
#pragma unroll
        for (int ri = 0; ri < 8; ++ri) { Ur[ri] = iv * ayr[ri]; Ui[ri] = iv * ayi[ri]; }
    }

    int laneD0 = ((quad >> 1)) * 16 + col;
    int laneD1 = (2 + (quad >> 1)) * 16 + col;
    int eb = (quad & 1) * 4;

    for (int k = 0; k < LNUM - 1; ++k) {
        float ck = ws[o_c + (size_t)b * 9 + k];
        float dk = ws[o_dd + (size_t)b * 9 + k];
        float Tn = ws[o_T + (size_t)b * 10 + k + 1];
        {
            union { _Float16 h[4]; unsigned long long u; } pk;
#pragma unroll
            for (int t = 0; t < 2; ++t) {
                int ld = t ? laneD1 : laneD0;
#pragma unroll
                for (int r = 0; r < 4; ++r) pk.h[r] = (_Float16)Ur[t * 4 + r];
                *(unsigned long long*)&Ubf[0][w][ld][eb] = pk.u;
#pragma unroll
                for (int r = 0; r < 4; ++r) pk.h[r] = (_Float16)Ui[t * 4 + r];
                *(unsigned long long*)&Ubf[1][w][ld][eb] = pk.u;
            }
        }
        __syncthreads();
        floatx4 ac[8];
#pragma unroll
        for (int i = 0; i < 8; ++i) ac[i] = (floatx4){0.f, 0.f, 0.f, 0.f};
#pragma unroll
        for (int ks = 0; ks < 8; ++ks) {
            half8 urh = *(const half8*)&Ubf[0][ks][lane][0];
            half8 uih = *(const half8*)&Ubf[1][ks][lane][0];
            MFMA16(Ar8[0][ks], urh, ac[0]);
            MFMA16(Ai8[0][ks], uih, ac[1]);
            MFMA16(Ar8[0][ks], uih, ac[2]);
            MFMA16(Ai8[0][ks], urh, ac[3]);
            MFMA16(Ar8[1][ks], urh, ac[4]);
            MFMA16(Ai8[1][ks], uih, ac[5]);
            MFMA16(Ar8[1][ks], uih, ac[6]);
            MFMA16(Ai8[1][ks], urh, ac[7]);
        }
        float wr[8], wi[8], sg[8];
        float p1 = 0.f, p2 = 0.f, p3 = 0.f;
#pragma unroll
        for (int t = 0; t < 2; ++t)
#pragma unroll
            for (int r = 0; r < 4; ++r) {
                int ri = t * 4 + r;
                wr[ri] = ac[t * 4 + 0][r] - ac[t * 4 + 1][r];
                wi[ri] = ac[t * 4 + 2][r] + ac[t * 4 + 3][r];
                sg[ri] = frcp(fmaf(eps, Dv[ri], lam[ri] + EPS_Sf));
                p1 += ayr[ri] * Ur[ri] + ayi[ri] * Ui[ri];
                p2 += Ur[ri] * wr[ri] + Ui[ri] * wi[ri];
                p3 += Dv[ri] * sg[ri];
            }
        p1 += __shfl_xor(p1, 16); p1 += __shfl_xor(p1, 32);
        p2 += __shfl_xor(p2, 16); p2 += __shfl_xor(p2, 32);
        p3 += __shfl_xor(p3, 16); p3 += __shfl_xor(p3, 32);
        if (lane < 16) {
            redv[col][w * 3]     = p1;
            redv[col][w * 3 + 1] = p2;
            redv[col][w * 3 + 2] = p3;
        }
        __syncthreads();
        float s[3] = {0.f, 0.f, 0.f};
#pragma unroll
        for (int j = 0; j < 7; ++j) {
            floatx4 v4 = *(const floatx4*)&redv[col][j * 4];
#pragma unroll
            for (int e = 0; e < 4; ++e) s[(j * 4 + e) % 3] += v4[e];
        }
        float eps1 = fmaxf(yn - 2.f * s[0] + s[1], 0.f);
        eps = atot * frcp(b0v + eps1 + s[2] + EPS_Sf);
        float ck1 = ck + 1.f;
#pragma unroll
        for (int ri = 0; ri < 8; ++ri) {
            lam[ri] = ck1 * frcp(dk + Ur[ri] * Ur[ri] + Ui[ri] * Ui[ri] + sg[ri] + EPS_Sf);
            float iv = eps * frcp(fmaf(eps, Tn, lam[ri] + EPS_Sf));
            Ur[ri] = iv * (Tn * Ur[ri] - wr[ri] + ayr[ri]);
            Ui[ri] = iv * (Tn * Ui[ri] - wi[ri] + ayi[ri]);
        }
    }
    float lm = 0.f;
#pragma unroll
    for (int t = 0; t < 2; ++t) {
        float4 v;
        v.x = sqrtf(Ur[t * 4 + 0] * Ur[t * 4 + 0] + Ui[t * 4 + 0] * Ui[t * 4 + 0]);
        v.y = sqrtf(Ur[t * 4 + 1] * Ur[t * 4 + 1] + Ui[t * 4 + 1] * Ui[t * 4 + 1]);
        v.z = sqrtf(Ur[t * 4 + 2] * Ur[t * 4 + 2] + Ui[t * 4 + 2] * Ui[t * 4 + 2]);
        v.w = sqrtf(Ur[t * 4 + 3] * Ur[t * 4 + 3] + Ui[t * 4 + 3] * Ui[t * 4 + 3]);
        *(float4*)&ws[o_Ua + (size_t)b * M_N + w * 32 + t * 16 + quad * 4] = v;
        lm = fmaxf(lm, fmaxf(fmaxf(v.x, v.y), fmaxf(v.z, v.w)));
    }
#pragma unroll
    for (int off = 32; off >= 1; off >>= 1) lm = fmaxf(lm, __shfl_xor(lm, off));
    if (lane == 0) redm[w] = lm;
    __syncthreads();
    if (tid == 0) {
        float mx = redm[0];
#pragma unroll
        for (int i = 1; i < 8; ++i) mx = fmaxf(mx, redm[i]);
        atomicMax((unsigned int*)(ws + o_gm), __float_as_uint(mx));
    }
}

// ---------------- K6: normalize ----------------
__global__ void k_norm(const float* __restrict__ ws, float* __restrict__ out) {
    size_t i = (size_t)blockIdx.x * 256 + threadIdx.x;
    float gm = __uint_as_float(*(const unsigned int*)(ws + o_gm));
    out[i] = ws[o_Ua + i] / (gm + 1e-8f);
}

extern "C" void kernel_launch(void* const* d_in, const int* in_sizes, int n_in,
                              void* d_out, int out_size, void* d_ws, size_t ws_size,
                              hipStream_t stream) {
    (void)in_sizes; (void)n_in; (void)out_size; (void)ws_size;
    const float* Yr  = (const float*)d_in[0];
    const float* Yi  = (const float*)d_in[1];
    const float* Ar  = (const float*)d_in[2];
    const float* Ai  = (const float*)d_in[3];
    const float* w1  = (const float*)d_in[4];
    const float* b1  = (const float*)d_in[5];
    const float* w2  = (const float*)d_in[6];
    const float* b2  = (const float*)d_in[7];
    const float* hcw = (const float*)d_in[8];
    const float* hcb = (const float*)d_in[9];
    const float* hdw = (const float*)d_in[10];
    const float* hdb = (const float*)d_in[11];
    const float* hTw = (const float*)d_in[12];
    const float* hTb = (const float*)d_in[13];
    const float* a0  = (const float*)d_in[14];
    const float* b0  = (const float*)d_in[15];
    float* ws = (float*)d_ws;
    float* out = (float*)d_out;

    k_pre   <<<584, 256, 0, stream>>>(Ar, Ai, Yr, Yi, w2, ws);
    k_conv12<<<2048, 256, 0, stream>>>(w1, b1, b2, ws);
    k_fred  <<<512, 256, 0, stream>>>(ws);
    k_cdt   <<<224, 256, 0, stream>>>(hcw, hcb, hdw, hdb, hTw, hTb, ws, out);
    k_iter  <<<128, 512, 0, stream>>>(a0, b0, ws);
    k_norm  <<<2048, 256, 0, stream>>>(ws, out);
}